// Round 13
// baseline (135.908 us; speedup 1.0000x reference)
//
#include <hip/hip_runtime.h>

#define TEMP    0.5f
#define LOG2E   1.4426950408889634f
#define C2      (LOG2E / TEMP)        /* t = dot * C2 */
#define MSHIFT  160.0f                /* fixed base-2 softmax shift */
#define LN2     0.6931471805599453f
#define NROWS   16384
#define BHALF   8192
#define DDIM    128
#define PREPB   2048                  /* k_prep blocks = 524288/256 */

typedef __bf16 bf16x8 __attribute__((ext_vector_type(8)));
typedef float  f32x16 __attribute__((ext_vector_type(16)));
typedef float  f32x2  __attribute__((ext_vector_type(2)));

__device__ __forceinline__ float fexp2(float x) {
#if __has_builtin(__builtin_amdgcn_exp2f)
  return __builtin_amdgcn_exp2f(x);
#else
  return exp2f(x);
#endif
}

__device__ __forceinline__ unsigned short f2bf(float f) {
  unsigned int u = __float_as_uint(f);
  unsigned int r = (u + 0x7FFFu + ((u >> 16) & 1u)) >> 16;  // RNE
  return (unsigned short)r;
}

// ---------------------------------------------------------------------------
// zbF frag-major layout: for row r, k-index k:
//   g = r/32, lo = r%32, khi = k/8, j = k%8
//   short index = g*4096 + khi*256 + lo*8 + j
// ---------------------------------------------------------------------------

__global__ void k_prep(const float* __restrict__ zi, const float* __restrict__ zj,
                       unsigned short* __restrict__ zbF,
                       float* __restrict__ S, float* __restrict__ Pp) {
  const int t   = blockIdx.x * 256 + threadIdx.x;   // 0..524287 float4 groups
  const int row = t >> 5;                           // 32 float4 per 128-elt row
  const int k0  = (t & 31) * 4;
  const float* src = (row < BHALF) ? (zi + (size_t)row * DDIM)
                                   : (zj + (size_t)(row - BHALF) * DDIM);
  float4 v = *reinterpret_cast<const float4*>(src + k0);

  const int g = row >> 5, lo = row & 31, khi = k0 >> 3, j0 = k0 & 7;
  ushort4 o;
  o.x = f2bf(v.x); o.y = f2bf(v.y); o.z = f2bf(v.z); o.w = f2bf(v.w);
  *reinterpret_cast<ushort4*>(zbF + (size_t)g * 4096 + khi * 256 + lo * 8 + j0) = o;

  float dot = 0.f;
  if (row < BHALF) {
    float4 w = *reinterpret_cast<const float4*>(zj + (size_t)row * DDIM + k0);
    dot = fmaf(v.x, w.x, fmaf(v.y, w.y, fmaf(v.z, w.z, v.w * w.w)));
  }
#pragma unroll
  for (int m = 32; m >= 1; m >>= 1) dot += __shfl_xor(dot, m, 64);
  __shared__ float red[4];
  if ((threadIdx.x & 63) == 0) red[threadIdx.x >> 6] = dot;
  __syncthreads();
  if (threadIdx.x == 0) Pp[blockIdx.x] = red[0] + red[1] + red[2] + red[3];

  if (t < NROWS) S[t] = 0.f;
}

// ---------------------------------------------------------------------------
// k_main (round 13): REGISTER-RICH INTRA-WAVE PIPELINE at occupancy 1.
// __launch_bounds__(256,1) -> 512-VGPR budget/wave. 256 blocks (1/CU), each
// wave: 128 persistent rows (b[4][8]) x 2048 cols (64 iters x 32).
// Per iteration: FOUR independent MFMA chains (covers >=128cy dependent
// latency) build this iter's accs, source-interleaved per-ks-step with the
// exp of the PREVIOUS iter's 4 accs (4 exp-units ~ 120cy VALU vs 4 MFMA
// ~128cy pipe per step) + 1 a-dbuf reload. Peak live ~360 regs < 450
// no-spill bound (m08).
// WHY NOW: r1/r2/r5's interleaves died of spill at 2 waves/SIMD (256-reg
// budget); r12 proved 2-wave TLP overlap unreachable (anti-phase null).
// This is the same idea with the register budget that makes it legal.
// FROZEN: no software phase barriers (r7/r8/r10); no thin waves (r6).
// ---------------------------------------------------------------------------

// exp one pk-pair (elements 2k, 2k+1) of acc e into s.
template <bool MASK>
__device__ __forceinline__ void expStep(const f32x16& e, int k, f32x2& s,
                                        int d, int hi) {
  f32x2 u;
  u.x = e[2 * k];
  u.y = e[2 * k + 1];
  const f32x2 c2v = {C2, C2};
  const f32x2 msv = {-MSHIFT, -MSHIFT};
  u = __builtin_elementwise_fma(u, c2v, msv);        // v_pk_fma_f32
  f32x2 ev;
  ev.x = fexp2(u.x);
  ev.y = fexp2(u.y);
  if (MASK) {
    const int r0 = 2 * k, r1 = 2 * k + 1;
    if (((r0 & 3) + 8 * (r0 >> 2) + 4 * hi) == d) ev.x = 0.f;  // C/D reg map
    if (((r1 & 3) + 8 * (r1 >> 2) + 4 * hi) == d) ev.y = 0.f;
  }
  s += ev;                                            // v_pk_add_f32
}

#define MFMA_ __builtin_amdgcn_mfma_f32_32x32x16_bf16

// One pipelined iteration: build x0..x3 (4 chains over ks) from aC x b[0..3];
// per ks-step interleave 4 exp-units of the previous iter's e0..e3 and
// (optionally) one reload of aN[ks] for iteration after next use.
template <bool MASK, bool RELOAD>
__device__ __forceinline__ void phase(const bf16x8 (&aC)[8], bf16x8 (&aN)[8],
                                      const bf16x8 (&b)[4][8], const f32x16& kZ,
                                      f32x16& x0, f32x16& x1, f32x16& x2, f32x16& x3,
                                      const f32x16& e0, const f32x16& e1,
                                      const f32x16& e2, const f32x16& e3,
                                      f32x2 (&s)[4],
                                      const unsigned short* __restrict__ rp,
                                      int d0, int d1, int d2, int d3, int hi) {
  x0 = MFMA_(aC[0], b[0][0], kZ, 0, 0, 0);
  x1 = MFMA_(aC[0], b[1][0], kZ, 0, 0, 0);
  x2 = MFMA_(aC[0], b[2][0], kZ, 0, 0, 0);
  x3 = MFMA_(aC[0], b[3][0], kZ, 0, 0, 0);
  if constexpr (RELOAD) aN[0] = *reinterpret_cast<const bf16x8*>(rp);
  expStep<MASK>(e0, 0, s[0], d0, hi);
  expStep<MASK>(e1, 0, s[1], d1, hi);
  expStep<MASK>(e2, 0, s[2], d2, hi);
  expStep<MASK>(e3, 0, s[3], d3, hi);
#pragma unroll
  for (int ks = 1; ks < 8; ++ks) {
    x0 = MFMA_(aC[ks], b[0][ks], x0, 0, 0, 0);
    x1 = MFMA_(aC[ks], b[1][ks], x1, 0, 0, 0);
    x2 = MFMA_(aC[ks], b[2][ks], x2, 0, 0, 0);
    x3 = MFMA_(aC[ks], b[3][ks], x3, 0, 0, 0);
    if constexpr (RELOAD)
      aN[ks] = *reinterpret_cast<const bf16x8*>(rp + (size_t)ks * 512);
    expStep<MASK>(e0, ks, s[0], d0, hi);
    expStep<MASK>(e1, ks, s[1], d1, hi);
    expStep<MASK>(e2, ks, s[2], d2, hi);
    expStep<MASK>(e3, ks, s[3], d3, hi);
  }
}

// mask-dispatching wrapper: drE = diag offset of the iteration being exp'd.
template <bool RELOAD>
__device__ __forceinline__ void phaseD(const bf16x8 (&aC)[8], bf16x8 (&aN)[8],
                                       const bf16x8 (&b)[4][8], const f32x16& kZ,
                                       f32x16& x0, f32x16& x1, f32x16& x2, f32x16& x3,
                                       const f32x16& e0, const f32x16& e1,
                                       const f32x16& e2, const f32x16& e3,
                                       f32x2 (&s)[4],
                                       const unsigned short* __restrict__ rp,
                                       int drE, int lo, int hi) {
  if ((unsigned)drE >= 128u) {
    phase<false, RELOAD>(aC, aN, b, kZ, x0, x1, x2, x3, e0, e1, e2, e3, s, rp,
                         -1, -1, -1, -1, hi);
  } else {
    const int rtd = drE >> 5;
    phase<true, RELOAD>(aC, aN, b, kZ, x0, x1, x2, x3, e0, e1, e2, e3, s, rp,
                        rtd == 0 ? lo : -1, rtd == 1 ? lo : -1,
                        rtd == 2 ? lo : -1, rtd == 3 ? lo : -1, hi);
  }
}

// prologue: build only (+ reload of the next a-buffer), nothing to exp.
__device__ __forceinline__ void buildPre(const bf16x8 (&aC)[8], bf16x8 (&aN)[8],
                                         const bf16x8 (&b)[4][8], const f32x16& kZ,
                                         f32x16& x0, f32x16& x1, f32x16& x2, f32x16& x3,
                                         const unsigned short* __restrict__ rp) {
  x0 = MFMA_(aC[0], b[0][0], kZ, 0, 0, 0);
  x1 = MFMA_(aC[0], b[1][0], kZ, 0, 0, 0);
  x2 = MFMA_(aC[0], b[2][0], kZ, 0, 0, 0);
  x3 = MFMA_(aC[0], b[3][0], kZ, 0, 0, 0);
  aN[0] = *reinterpret_cast<const bf16x8*>(rp);
#pragma unroll
  for (int ks = 1; ks < 8; ++ks) {
    x0 = MFMA_(aC[ks], b[0][ks], x0, 0, 0, 0);
    x1 = MFMA_(aC[ks], b[1][ks], x1, 0, 0, 0);
    x2 = MFMA_(aC[ks], b[2][ks], x2, 0, 0, 0);
    x3 = MFMA_(aC[ks], b[3][ks], x3, 0, 0, 0);
    aN[ks] = *reinterpret_cast<const bf16x8*>(rp + (size_t)ks * 512);
  }
}

// epilogue: exp-only drain of the final iteration's accs.
template <bool MASK>
__device__ __forceinline__ void expAll(const f32x16& e0, const f32x16& e1,
                                       const f32x16& e2, const f32x16& e3,
                                       f32x2 (&s)[4], int d0, int d1, int d2,
                                       int d3, int hi) {
#pragma unroll
  for (int k = 0; k < 8; ++k) {
    expStep<MASK>(e0, k, s[0], d0, hi);
    expStep<MASK>(e1, k, s[1], d1, hi);
    expStep<MASK>(e2, k, s[2], d2, hi);
    expStep<MASK>(e3, k, s[3], d3, hi);
  }
}

__global__ __launch_bounds__(256, 1)
void k_main(const unsigned short* __restrict__ zbF, float* __restrict__ S) {
  const int wave = threadIdx.x >> 6;
  const int lane = threadIdx.x & 63;
  const int lo = lane & 31;
  const int hi = lane >> 5;
  const int rb = blockIdx.x & 31;       // 32 row blocks of 512 rows
  const int cc = blockIdx.x >> 5;       // 8 col chunks of 2048 cols
  const int row0w = rb * 512 + wave * 128;

  // persistent row frags (B operand): 4 row-tiles x 8 k-steps
  bf16x8 b[4][8];
#pragma unroll
  for (int rt = 0; rt < 4; ++rt) {
    const unsigned short* bp = zbF + (size_t)((row0w >> 5) + rt) * 4096 + hi * 256 + lo * 8;
#pragma unroll
    for (int ks = 0; ks < 8; ++ks)
      b[rt][ks] = *reinterpret_cast<const bf16x8*>(bp + ks * 512);
  }

  const f32x16 kZ = {};
  f32x2 s[4];
#pragma unroll
  for (int rt = 0; rt < 4; ++rt) { s[rt].x = 0.f; s[rt].y = 0.f; }

  const int c0base = cc * 2048;
  const unsigned short* abase = zbF + (size_t)(c0base >> 5) * 4096 + hi * 256 + lo * 8;

  bf16x8 aA[8], aB[8];
#pragma unroll
  for (int ks = 0; ks < 8; ++ks)
    aA[ks] = *reinterpret_cast<const bf16x8*>(abase + ks * 512);

  f32x16 xA0, xA1, xA2, xA3, xB0, xB1, xB2, xB3;

  // it = 0: build xA from aA; prefetch aB for it=1
  buildPre(aA, aB, b, kZ, xA0, xA1, xA2, xA3, abase + (size_t)4096);

  for (int p = 0; p < 31; ++p) {
    const int it1 = 2 * p + 1;          // uses aB, builds xB, exps iter 2p (xA)
    const int it2 = 2 * p + 2;          // uses aA, builds xA, exps it1 (xB)
    phaseD<true>(aB, aA, b, kZ, xB0, xB1, xB2, xB3, xA0, xA1, xA2, xA3, s,
                 abase + (size_t)it2 * 4096, c0base + 2 * p * 32 - row0w, lo, hi);
    phaseD<true>(aA, aB, b, kZ, xA0, xA1, xA2, xA3, xB0, xB1, xB2, xB3, s,
                 abase + (size_t)(it2 + 1) * 4096, c0base + it1 * 32 - row0w, lo, hi);
  }
  // it = 63: uses aB, builds xB, exps iter 62 (xA); no reload
  phaseD<false>(aB, aA, b, kZ, xB0, xB1, xB2, xB3, xA0, xA1, xA2, xA3, s,
                abase, c0base + 62 * 32 - row0w, lo, hi);
  // epilogue: exp iter 63 (xB)
  {
    const int drE = c0base + 63 * 32 - row0w;
    if ((unsigned)drE >= 128u) {
      expAll<false>(xB0, xB1, xB2, xB3, s, -1, -1, -1, -1, hi);
    } else {
      const int rtd = drE >> 5;
      expAll<true>(xB0, xB1, xB2, xB3, s, rtd == 0 ? lo : -1, rtd == 1 ? lo : -1,
                   rtd == 2 ? lo : -1, rtd == 3 ? lo : -1, hi);
    }
  }

  // row sums: fold hi halves, one atomic per row per col-chunk
#pragma unroll
  for (int rt = 0; rt < 4; ++rt) {
    float v = s[rt].x + s[rt].y;
    v += __shfl_xor(v, 32, 64);
    if (hi == 0) atomicAdd(&S[row0w + rt * 32 + lo], v);
  }
}

// ---------------------------------------------------------------------------
__global__ void k_fin(const float* __restrict__ S, const float* __restrict__ Pp,
                      float* __restrict__ out) {
  const int t = threadIdx.x;            // 1024 threads
  float q = 0.f;
  for (int r = t; r < NROWS; r += 1024)
    q += LN2 * (MSHIFT + __log2f(S[r]));
  for (int r = t; r < PREPB; r += 1024)
    q -= 4.0f * Pp[r];
  __shared__ float red[1024];
  red[t] = q;
  __syncthreads();
  for (int s2 = 512; s2 > 0; s2 >>= 1) {
    if (t < s2) red[t] += red[t + s2];
    __syncthreads();
  }
  if (t == 0) out[0] = red[0] / (float)NROWS;
}

// ---------------------------------------------------------------------------
extern "C" void kernel_launch(void* const* d_in, const int* in_sizes, int n_in,
                              void* d_out, int out_size, void* d_ws, size_t ws_size,
                              hipStream_t stream) {
  const float* zi = (const float*)d_in[0];
  const float* zj = (const float*)d_in[1];
  unsigned short* zbF = (unsigned short*)d_ws;                     // 4 MB
  float* S  = (float*)((char*)d_ws + (size_t)NROWS * DDIM * 2);    // 64 KB
  float* Pp = S + NROWS;                                           // 8 KB
  float* out = (float*)d_out;

  hipLaunchKernelGGL(k_prep, dim3(PREPB), dim3(256), 0, stream, zi, zj, zbF, S, Pp);
  hipLaunchKernelGGL(k_main, dim3(256),  dim3(256), 0, stream, zbF, S);
  hipLaunchKernelGGL(k_fin,  dim3(1),    dim3(1024), 0, stream, S, Pp, out);
}